// Round 3
// baseline (21.337 us; speedup 1.0000x reference)
//
#include <hip/hip_runtime.h>

#define B_ 8
#define N_ 256
#define D_ 128

// ---------------------------------------------------------------------------
// K1: A[r][f] = sum_d x[r][d]*W[d][f] + bias[f];  C[r][f] = sum_d x[r][d]*W[D+d][f]
// 256 blocks x 8 rows, 256 threads. No W staging: W columns stream from L2
// (128 KB/block, all 4 waves read the same stream -> L1 absorbs redundancy).
// Thread = (rq 0..3 -> 2 rows, cq 0..63 -> float4 of the 256 concat cols).
// x tile (4 KB) staged in LDS once; xs reads are wave-uniform broadcasts.
// ---------------------------------------------------------------------------
__global__ __launch_bounds__(256) void gemm_ac_kernel(
    const float* __restrict__ x, const float* __restrict__ W,
    const float* __restrict__ bias, float* __restrict__ A, float* __restrict__ C) {
    __shared__ float xs[8][D_];     // 4 KB

    const int tid = threadIdx.x;
    const int r0  = blockIdx.x * 8;
    const int rq  = tid >> 6;       // wave id -> rows {2rq, 2rq+1}
    const int cq  = tid & 63;       // float4 group over 256 concat cols
    const int halfC = cq >> 5;
    const int f   = (cq & 31) * 4;

    {   // stage x tile: 8 rows x 128 = 256 float4, one per thread
        const int row = tid >> 5;
        const int dq  = tid & 31;
        reinterpret_cast<float4*>(&xs[row][0])[dq] =
            *reinterpret_cast<const float4*>(x + (size_t)(r0 + row) * D_ + dq * 4);
    }
    __syncthreads();

    const float* __restrict__ Wp = W + (halfC ? D_ * D_ : 0) + f;
    const float* __restrict__ xr0 = &xs[rq * 2][0];
    const float* __restrict__ xr1 = &xs[rq * 2 + 1][0];

    float4 acc0 = make_float4(0.f, 0.f, 0.f, 0.f);
    float4 acc1 = make_float4(0.f, 0.f, 0.f, 0.f);

    #pragma unroll 4
    for (int c = 0; c < 32; ++c) {              // 4 d per chunk
        const float4 xv0 = *reinterpret_cast<const float4*>(xr0 + c * 4);
        const float4 xv1 = *reinterpret_cast<const float4*>(xr1 + c * 4);
        #pragma unroll
        for (int k = 0; k < 4; ++k) {
            const float4 wv = *reinterpret_cast<const float4*>(
                Wp + (size_t)(c * 4 + k) * D_);
            const float x0 = (&xv0.x)[k];
            const float x1 = (&xv1.x)[k];
            acc0.x += x0 * wv.x; acc0.y += x0 * wv.y;
            acc0.z += x0 * wv.z; acc0.w += x0 * wv.w;
            acc1.x += x1 * wv.x; acc1.y += x1 * wv.y;
            acc1.z += x1 * wv.z; acc1.w += x1 * wv.w;
        }
    }

    const int row0 = r0 + rq * 2;
    if (halfC) {
        *reinterpret_cast<float4*>(C + (size_t)row0 * D_ + f)       = acc0;
        *reinterpret_cast<float4*>(C + (size_t)(row0 + 1) * D_ + f) = acc1;
    } else {
        const float4 bv = *reinterpret_cast<const float4*>(bias + f);
        acc0.x += bv.x; acc0.y += bv.y; acc0.z += bv.z; acc0.w += bv.w;
        acc1.x += bv.x; acc1.y += bv.y; acc1.z += bv.z; acc1.w += bv.w;
        *reinterpret_cast<float4*>(A + (size_t)row0 * D_ + f)       = acc0;
        *reinterpret_cast<float4*>(A + (size_t)(row0 + 1) * D_ + f) = acc1;
    }
}

// ---------------------------------------------------------------------------
// K2: out[b,i,f] = sum_j relu(A'[b,i,f] + C[b,j,f])   (bias folded into A)
// 512 blocks x 4 rows, 256 threads = 32 fq (float4) x 4 ir x 2 jg.
// Thread owns (i, f4) for its 128-j half serially: 12 VALU per 16B L2 load,
// zero LDS in the main loop, one LDS exchange + 2 barriers at the end.
// ---------------------------------------------------------------------------
__global__ __launch_bounds__(256) void reduce_edges_kernel(
    const float* __restrict__ A, const float* __restrict__ C,
    float* __restrict__ out) {
    __shared__ float4 part[4][32];   // 2 KB

    const int blk = blockIdx.x;      // 0..511
    const int b   = blk >> 6;
    const int i0  = (blk & 63) * 4;
    const int tid = threadIdx.x;
    const int fq  = tid & 31;
    const int f   = fq * 4;
    const int ir  = (tid >> 5) & 3;
    const int jg  = tid >> 7;        // 0,1

    const size_t rowbase = ((size_t)(b * N_ + i0 + ir)) * D_ + f;
    const float4 av = *reinterpret_cast<const float4*>(A + rowbase);
    float4 acc = make_float4(0.f, 0.f, 0.f, 0.f);

    const float* __restrict__ Cb =
        C + (size_t)b * N_ * D_ + (size_t)jg * (N_ / 2) * D_ + f;
    #pragma unroll 8
    for (int j = 0; j < N_ / 2; ++j) {
        const float4 cv = *reinterpret_cast<const float4*>(Cb + (size_t)j * D_);
        acc.x += fmaxf(av.x + cv.x, 0.f);
        acc.y += fmaxf(av.y + cv.y, 0.f);
        acc.z += fmaxf(av.z + cv.z, 0.f);
        acc.w += fmaxf(av.w + cv.w, 0.f);
    }

    if (jg == 1) part[ir][fq] = acc;
    __syncthreads();
    if (jg == 0) {
        const float4 p = part[ir][fq];
        acc.x += p.x; acc.y += p.y; acc.z += p.z; acc.w += p.w;
        *reinterpret_cast<float4*>(out + rowbase) = acc;
    }
}

// Fallback (only if workspace too small): fully fused, recomputes C per row.
__global__ __launch_bounds__(128) void fused_naive_kernel(
    const float* __restrict__ x, const float* __restrict__ W,
    const float* __restrict__ bias, float* __restrict__ out) {
    const int r = blockIdx.x;
    const int b = r / N_;
    const int f = threadIdx.x;
    const float* __restrict__ xi = x + (size_t)r * D_;
    float a = bias[f];
    for (int d = 0; d < D_; ++d) a += xi[d] * W[d * D_ + f];
    float acc = 0.0f;
    const float* __restrict__ xb = x + (size_t)b * N_ * D_;
    for (int j = 0; j < N_; ++j) {
        const float* __restrict__ xj = xb + (size_t)j * D_;
        float c = 0.0f;
        for (int d = 0; d < D_; ++d) c += xj[d] * W[(D_ + d) * D_ + f];
        acc += fmaxf(a + c, 0.0f);
    }
    out[(size_t)r * D_ + f] = acc;
}

extern "C" void kernel_launch(void* const* d_in, const int* in_sizes, int n_in,
                              void* d_out, int out_size, void* d_ws, size_t ws_size,
                              hipStream_t stream) {
    const float* x    = (const float*)d_in[0];   // (B, N, D) fp32
    const float* W    = (const float*)d_in[1];   // (2D, D)   fp32
    const float* bias = (const float*)d_in[2];   // (D,)      fp32
    float* out = (float*)d_out;                  // (B, N, D) fp32

    const size_t elems = (size_t)B_ * N_ * D_;
    const size_t need  = 2 * elems * sizeof(float);

    if (ws_size >= need) {
        float* A = (float*)d_ws;
        float* C = A + elems;
        gemm_ac_kernel<<<(B_ * N_) / 8, 256, 0, stream>>>(x, W, bias, A, C);
        reduce_edges_kernel<<<(B_ * N_) / 4, 256, 0, stream>>>(A, C, out);
    } else {
        fused_naive_kernel<<<B_ * N_, D_, 0, stream>>>(x, W, bias, out);
    }
}